// Round 2
// baseline (9069.551 us; speedup 1.0000x reference)
//
#include <hip/hip_runtime.h>

// Problem constants
#define SEQ   2048
#define NBAT  2
#define MTOT  4096        // NBAT*SEQ
#define DIMC  1024
#define DFFC  4096
#define NEXP  8
#define NHEAD 16
//
// ws layout (floats), lifetime-overlapped, peak ~118 MB:
//  A [0,        16,777,216) : im2col(12.58M)+yconv(A[12.58M:16.77M))
//                             -> ctx(A[0:4.19M)) -> MoE hidden (full A)
//  B [16.77M,   29,360,128) : wpack(3.15M) -> qkv(full B)
//                             -> res1|x1|moe (3 x 4.19M)
//  probs [29.36M, +32K)

// ---------------------------------------------------------------------------
// Generic tiled fp32 GEMM: C[M,N] = A[M,K] @ B + epilogue
//   BT=false: B is (K,N) row-major.  BT=true: B is (N,K) row-major (linear W).
// Epilogue: +bias[N], relu, *row_scale[m], +residual[M,N], +=C (accum)
// Requires M%128==0, N%128==0, K%16==0 (true for all calls here).
// ---------------------------------------------------------------------------
template<bool BT>
__global__ __launch_bounds__(256)
void sgemm_kernel(const float* __restrict__ A, const float* __restrict__ B,
                  float* __restrict__ C, int K, int lda, int ldb, int ldc,
                  const float* __restrict__ bias,
                  const float* __restrict__ residual,
                  const float* __restrict__ row_scale, int rs_stride,
                  int do_relu, int do_accum)
{
  constexpr int BK = 16;
  __shared__ float As[BK][132];   // stride 132: 16B-aligned rows, broken pow2
  __shared__ float Bs[BK][132];
  const int t  = threadIdx.x;
  const int m0 = blockIdx.y * 128;
  const int n0 = blockIdx.x * 128;
  const int tx = t & 15, ty = t >> 4;
  const int ar  = t >> 2;          // 0..63
  const int akq = (t & 3) << 2;    // 0,4,8,12

  float acc[8][8];
#pragma unroll
  for (int i = 0; i < 8; ++i)
#pragma unroll
    for (int j = 0; j < 8; ++j) acc[i][j] = 0.f;

  for (int k0 = 0; k0 < K; k0 += BK) {
    // A tile: 128 rows x 16 k, store transposed As[k][m]
#pragma unroll
    for (int p = 0; p < 2; ++p) {
      const int row = ar + p * 64;
      const float4 v = *(const float4*)&A[(size_t)(m0 + row) * lda + k0 + akq];
      As[akq + 0][row] = v.x; As[akq + 1][row] = v.y;
      As[akq + 2][row] = v.z; As[akq + 3][row] = v.w;
    }
    if (!BT) {
      // B tile: 16 k-rows x 128 n, already k-major
#pragma unroll
      for (int p = 0; p < 2; ++p) {
        const int row = (t >> 5) + p * 8;
        const int c   = (t & 31) << 2;
        const float4 v = *(const float4*)&B[(size_t)(k0 + row) * ldb + n0 + c];
        *(float4*)&Bs[row][c] = v;
      }
    } else {
      // B is (N,K): read 128 n-rows x 16 k, transpose into Bs[k][n]
#pragma unroll
      for (int p = 0; p < 2; ++p) {
        const int col = ar + p * 64;
        const float4 v = *(const float4*)&B[(size_t)(n0 + col) * ldb + k0 + akq];
        Bs[akq + 0][col] = v.x; Bs[akq + 1][col] = v.y;
        Bs[akq + 2][col] = v.z; Bs[akq + 3][col] = v.w;
      }
    }
    __syncthreads();
#pragma unroll
    for (int k = 0; k < BK; ++k) {
      float a[8], b[8];
      *(float4*)&a[0] = *(const float4*)&As[k][ty * 8];
      *(float4*)&a[4] = *(const float4*)&As[k][ty * 8 + 4];
      *(float4*)&b[0] = *(const float4*)&Bs[k][tx * 8];
      *(float4*)&b[4] = *(const float4*)&Bs[k][tx * 8 + 4];
#pragma unroll
      for (int i = 0; i < 8; ++i)
#pragma unroll
        for (int j = 0; j < 8; ++j)
          acc[i][j] = __builtin_fmaf(a[i], b[j], acc[i][j]);
    }
    __syncthreads();
  }

  const int m_base = m0 + ty * 8;
  const int n_base = n0 + tx * 8;
#pragma unroll
  for (int i = 0; i < 8; ++i) {
    const int m = m_base + i;
    float rsv = 1.f;
    if (row_scale) rsv = row_scale[(size_t)m * rs_stride];
    float* cp = &C[(size_t)m * ldc + n_base];
    const float* rp = residual ? &residual[(size_t)m * ldc + n_base] : nullptr;
#pragma unroll
    for (int q = 0; q < 2; ++q) {
      float r0 = acc[i][q * 4 + 0], r1 = acc[i][q * 4 + 1];
      float r2 = acc[i][q * 4 + 2], r3 = acc[i][q * 4 + 3];
      if (bias) {
        const float4 bb = *(const float4*)&bias[n_base + q * 4];
        r0 += bb.x; r1 += bb.y; r2 += bb.z; r3 += bb.w;
      }
      if (do_relu) {
        r0 = fmaxf(r0, 0.f); r1 = fmaxf(r1, 0.f);
        r2 = fmaxf(r2, 0.f); r3 = fmaxf(r3, 0.f);
      }
      r0 *= rsv; r1 *= rsv; r2 *= rsv; r3 *= rsv;
      if (rp) {
        const float4 rr = *(const float4*)&rp[q * 4];
        r0 += rr.x; r1 += rr.y; r2 += rr.z; r3 += rr.w;
      }
      if (do_accum) {
        const float4 oo = *(const float4*)&cp[q * 4];
        r0 += oo.x; r1 += oo.y; r2 += oo.z; r3 += oo.w;
      }
      float4 w4; w4.x = r0; w4.y = r1; w4.z = r2; w4.w = r3;
      *(float4*)&cp[q * 4] = w4;
    }
  }
}

// ---------------------------------------------------------------------------
// conv weight repack: wpack[t*1024 + i][o] = conv_w[o][i][t]
// ---------------------------------------------------------------------------
__global__ __launch_bounds__(256)
void wpack_kernel(const float* __restrict__ cw, float* __restrict__ wp)
{
  const int idx = blockIdx.x * 256 + threadIdx.x;   // < 3072*1024
  if (idx >= 3072 * 1024) return;
  const int o  = idx & 1023;
  const int k  = idx >> 10;
  const int tt = k >> 10;
  const int i  = k & 1023;
  wp[idx] = cw[(size_t)o * 3072 + i * 3 + tt];
}

// ---------------------------------------------------------------------------
// im2col with zero padding (per batch): col[m][t*1024+i] = x[b, s+t-1, i]
// ---------------------------------------------------------------------------
__global__ __launch_bounds__(256)
void im2col_kernel(const float* __restrict__ x, float* __restrict__ col)
{
  const size_t idx = (size_t)blockIdx.x * 256 + threadIdx.x;  // < 4096*3072
  if (idx >= (size_t)MTOT * 3072) return;
  const int j  = (int)(idx % 3072);
  const int m  = (int)(idx / 3072);
  const int tt = j >> 10;
  const int i  = j & 1023;
  const int b  = m >> 11;
  const int s  = m & 2047;
  const int sr = s + tt - 1;
  float v = 0.f;
  if (sr >= 0 && sr < SEQ) v = x[((size_t)(b * SEQ + sr) << 10) + i];
  col[idx] = v;
}

// ---------------------------------------------------------------------------
// Fused flash-style attention, fp32.
// grid (S/64, H, B), block 256.  qkv row-major (M,3072): q|k|v thirds.
// Per block: 64 query rows of one (b,h).  Online softmax over K-tiles of 64.
// Thread t: qr = t>>2 (query row), quad = t&3 (owns 16 d-cols of ctx).
// K/V tiles in LDS with XOR-swizzle on float4 columns to break bank aliasing.
// ---------------------------------------------------------------------------
__global__ __launch_bounds__(256)
void attn_kernel(const float* __restrict__ qkv, float* __restrict__ ctx)
{
  const int qt = blockIdx.x, h = blockIdx.y, b = blockIdx.z;
  const int t = threadIdx.x;
  const int lane = t & 63;
  const int qr = t >> 2, quad = t & 3;
  __shared__ float Ks[64 * 64];
  __shared__ float Vs[64 * 64];
  const size_t base = (size_t)b * SEQ * 3072;
  const int hoff = h * 64;

  // Q row (64 floats) into registers; 4 lanes/quad read same row (L1 broadcast)
  float4 qreg[16];
  {
    const float* qrow = &qkv[base + (size_t)(qt * 64 + qr) * 3072 + hoff];
#pragma unroll
    for (int d4 = 0; d4 < 16; ++d4) qreg[d4] = *(const float4*)&qrow[d4 * 4];
  }

  float m_run = -1e30f, l_run = 0.f;
  float4 ctx4[4];
#pragma unroll
  for (int j = 0; j < 4; ++j) ctx4[j] = make_float4(0.f, 0.f, 0.f, 0.f);

  for (int kt = 0; kt < SEQ / 64; ++kt) {
    __syncthreads();   // protect Ks/Vs from previous iteration's readers
    // load K and V tiles (64 rows x 64 cols) as float4, swizzled columns
    for (int i = t; i < 64 * 16; i += 256) {
      const int r  = i >> 4;
      const int c4 = i & 15;
      const int cs = c4 ^ ((r >> 4) << 2);
      const float* src = &qkv[base + (size_t)(kt * 64 + r) * 3072 + 1024 + hoff + c4 * 4];
      *(float4*)&Ks[r * 64 + cs * 4] = *(const float4*)src;
      *(float4*)&Vs[r * 64 + cs * 4] = *(const float4*)&src[1024];  // V = K + 1024
    }
    __syncthreads();

    // scores: thread computes s[qr][k] for k = quad*16 .. +16
    float p[16];
    float tmax = -1e30f;
#pragma unroll
    for (int kk = 0; kk < 16; ++kk) {
      const int k = quad * 16 + kk;
      const float* krow = &Ks[k * 64];
      const int sw = (k >> 4) << 2;
      float a = 0.f;
#pragma unroll
      for (int d4 = 0; d4 < 16; ++d4) {
        const float4 kv = *(const float4*)&krow[(d4 ^ sw) * 4];
        a = __builtin_fmaf(qreg[d4].x, kv.x, a);
        a = __builtin_fmaf(qreg[d4].y, kv.y, a);
        a = __builtin_fmaf(qreg[d4].z, kv.z, a);
        a = __builtin_fmaf(qreg[d4].w, kv.w, a);
      }
      p[kk] = a * 0.125f;
      tmax = fmaxf(tmax, p[kk]);
    }
    // row max across the 4 quads (adjacent lanes)
    tmax = fmaxf(tmax, __shfl_xor(tmax, 1, 64));
    tmax = fmaxf(tmax, __shfl_xor(tmax, 2, 64));
    const float m_new = fmaxf(m_run, tmax);
    const float resc  = __expf(m_run - m_new);
    float l_tile = 0.f;
#pragma unroll
    for (int kk = 0; kk < 16; ++kk) { p[kk] = __expf(p[kk] - m_new); l_tile += p[kk]; }
    l_tile += __shfl_xor(l_tile, 1, 64);
    l_tile += __shfl_xor(l_tile, 2, 64);
    l_run = l_run * resc + l_tile;
    m_run = m_new;
#pragma unroll
    for (int j = 0; j < 4; ++j) {
      ctx4[j].x *= resc; ctx4[j].y *= resc; ctx4[j].z *= resc; ctx4[j].w *= resc;
    }
    // PV: ctx[qr][d] += sum_k p[qr][k] * V[k][d]; share p across quad via shfl
#pragma unroll
    for (int sq = 0; sq < 4; ++sq) {
#pragma unroll
      for (int kk = 0; kk < 16; ++kk) {
        const int k = sq * 16 + kk;
        const float pv = __shfl(p[kk], (lane & ~3) | sq, 64);
        const float* vrow = &Vs[k * 64];
        const int sw = (k >> 4) << 2;
#pragma unroll
        for (int j = 0; j < 4; ++j) {
          const int c4 = (quad * 4 + j) ^ sw;
          const float4 vv = *(const float4*)&vrow[c4 * 4];
          ctx4[j].x = __builtin_fmaf(pv, vv.x, ctx4[j].x);
          ctx4[j].y = __builtin_fmaf(pv, vv.y, ctx4[j].y);
          ctx4[j].z = __builtin_fmaf(pv, vv.z, ctx4[j].z);
          ctx4[j].w = __builtin_fmaf(pv, vv.w, ctx4[j].w);
        }
      }
    }
  }
  const float inv_l = 1.f / l_run;
  float* dst = &ctx[(size_t)((size_t)b * SEQ + qt * 64 + qr) * 1024 + hoff + quad * 16];
#pragma unroll
  for (int j = 0; j < 4; ++j) {
    float4 o = ctx4[j];
    o.x *= inv_l; o.y *= inv_l; o.z *= inv_l; o.w *= inv_l;
    *(float4*)&dst[j * 4] = o;
  }
}

// ---------------------------------------------------------------------------
// LayerNorm over rows of 1024: out = LN(in (+ res)) * g + b.  grid = rows.
// ---------------------------------------------------------------------------
__global__ __launch_bounds__(256)
void ln_kernel(const float* __restrict__ in, const float* __restrict__ res,
               const float* __restrict__ g, const float* __restrict__ bt,
               float* __restrict__ out)
{
  const int row = blockIdx.x, t = threadIdx.x;
  const size_t off = ((size_t)row << 10) + t * 4;
  float4 v = *(const float4*)&in[off];
  if (res) {
    const float4 r = *(const float4*)&res[off];
    v.x += r.x; v.y += r.y; v.z += r.z; v.w += r.w;
  }
  float s  = v.x + v.y + v.z + v.w;
  float ss = v.x * v.x + v.y * v.y + v.z * v.z + v.w * v.w;
#pragma unroll
  for (int o = 32; o; o >>= 1) {
    s  += __shfl_xor(s, o, 64);
    ss += __shfl_xor(ss, o, 64);
  }
  __shared__ float red[8];
  if ((t & 63) == 0) { red[(t >> 6) * 2] = s; red[(t >> 6) * 2 + 1] = ss; }
  __syncthreads();
  s  = red[0] + red[2] + red[4] + red[6];
  ss = red[1] + red[3] + red[5] + red[7];
  const float mu   = s * (1.f / 1024.f);
  const float var  = ss * (1.f / 1024.f) - mu * mu;
  const float rstd = rsqrtf(var + 1e-5f);
  const float4 gg = *(const float4*)&g[t * 4];
  const float4 bb = *(const float4*)&bt[t * 4];
  float4 o;
  o.x = (v.x - mu) * rstd * gg.x + bb.x;
  o.y = (v.y - mu) * rstd * gg.y + bb.y;
  o.z = (v.z - mu) * rstd * gg.z + bb.z;
  o.w = (v.w - mu) * rstd * gg.w + bb.w;
  *(float4*)&out[off] = o;
}

// ---------------------------------------------------------------------------
// MoE gate: probs[m, 0..7] = softmax(x[m,:] @ gate_w + gate_b). 1 wave / row.
// ---------------------------------------------------------------------------
__global__ __launch_bounds__(64)
void gate_kernel(const float* __restrict__ x, const float* __restrict__ gw,
                 const float* __restrict__ gb, float* __restrict__ probs)
{
  const int m = blockIdx.x, lane = threadIdx.x;
  float acc[8];
#pragma unroll
  for (int e = 0; e < 8; ++e) acc[e] = 0.f;
  for (int k = lane; k < 1024; k += 64) {
    const float xv = x[((size_t)m << 10) + k];
    const float4 g0 = *(const float4*)&gw[k * 8];
    const float4 g1 = *(const float4*)&gw[k * 8 + 4];
    acc[0] = __builtin_fmaf(xv, g0.x, acc[0]);
    acc[1] = __builtin_fmaf(xv, g0.y, acc[1]);
    acc[2] = __builtin_fmaf(xv, g0.z, acc[2]);
    acc[3] = __builtin_fmaf(xv, g0.w, acc[3]);
    acc[4] = __builtin_fmaf(xv, g1.x, acc[4]);
    acc[5] = __builtin_fmaf(xv, g1.y, acc[5]);
    acc[6] = __builtin_fmaf(xv, g1.z, acc[6]);
    acc[7] = __builtin_fmaf(xv, g1.w, acc[7]);
  }
#pragma unroll
  for (int o = 32; o; o >>= 1)
#pragma unroll
    for (int e = 0; e < 8; ++e) acc[e] += __shfl_xor(acc[e], o, 64);
  float lg[8], mx = -1e30f;
#pragma unroll
  for (int e = 0; e < 8; ++e) { lg[e] = acc[e] + gb[e]; mx = fmaxf(mx, lg[e]); }
  float se = 0.f;
#pragma unroll
  for (int e = 0; e < 8; ++e) { lg[e] = __expf(lg[e] - mx); se += lg[e]; }
  const float inv = 1.f / se;
  if (lane < 8) probs[(size_t)m * 8 + lane] = lg[lane] * inv;
}

// ---------------------------------------------------------------------------
extern "C" void kernel_launch(void* const* d_in, const int* in_sizes, int n_in,
                              void* d_out, int out_size, void* d_ws, size_t ws_size,
                              hipStream_t stream)
{
  const float* x      = (const float*)d_in[0];
  const float* conv_w = (const float*)d_in[1];
  const float* conv_b = (const float*)d_in[2];
  const float* wqkv   = (const float*)d_in[3];
  const float* bqkv   = (const float*)d_in[4];
  const float* wo     = (const float*)d_in[5];
  const float* bo     = (const float*)d_in[6];
  const float* ln1_g  = (const float*)d_in[7];
  const float* ln1_b  = (const float*)d_in[8];
  const float* gate_w = (const float*)d_in[9];
  const float* gate_b = (const float*)d_in[10];
  const float* w1     = (const float*)d_in[11];
  const float* b1     = (const float*)d_in[12];
  const float* w2     = (const float*)d_in[13];
  const float* b2     = (const float*)d_in[14];
  const float* ln2_g  = (const float*)d_in[15];
  const float* ln2_b  = (const float*)d_in[16];
  float* out = (float*)d_out;
  float* ws  = (float*)d_ws;

  // Lifetime-overlapped scratch regions (floats). Peak footprint ~118 MB.
  float* A = ws;                        // 16,777,216 floats
  float* B = ws + 16777216;             // 12,582,912 floats
  float* probs = B + 12582912;          //     32,768 floats
  // Region A phases:
  float* im2c  = A;                     // [0, 12.58M)  conv staging
  float* yconv = A + 12582912;          // [12.58M, 16.77M)  conv output
  float* ctxb  = A;                     // [0, 4.19M)   attention output (im2c dead)
  float* hbuf  = A;                     // [0, 16.77M)  MoE hidden (ctx/yconv dead)
  // Region B phases:
  float* wpk   = B;                     // [0, 3.15M)   packed conv weights
  float* qkvb  = B;                     // [0, 12.58M)  qkv (wpk dead)
  float* res1  = B;                     // [0, 4.19M)   post-attn residual sum
  float* x1    = B + 4194304;           // [4.19M, 8.39M)  LN1 output
  float* moe   = B + 8388608;           // [8.39M, 12.58M) MoE accumulator

  const dim3 blk256(256);

  // 1) conv as GEMM: repack weights + im2col, then (4096x3072)@(3072x1024)
  wpack_kernel<<<dim3((3072 * 1024 + 255) / 256), blk256, 0, stream>>>(conv_w, wpk);
  im2col_kernel<<<dim3((MTOT * 3072 + 255) / 256), blk256, 0, stream>>>(x, im2c);
  sgemm_kernel<false><<<dim3(1024 / 128, MTOT / 128), blk256, 0, stream>>>(
      im2c, wpk, yconv, 3072, 3072, 1024, 1024,
      conv_b, nullptr, nullptr, 0, 0, 0);

  // 2) QKV projection: (4096x1024) @ wqkv^T (3072x1024) + bqkv  (wpk now dead)
  sgemm_kernel<true><<<dim3(3072 / 128, MTOT / 128), blk256, 0, stream>>>(
      yconv, wqkv, qkvb, 1024, 1024, 1024, 3072,
      bqkv, nullptr, nullptr, 0, 0, 0);

  // 3) fused attention -> ctx (B,S,D)   (im2c dead, ctx aliases A[0:4.19M))
  attn_kernel<<<dim3(SEQ / 64, NHEAD, NBAT), blk256, 0, stream>>>(qkvb, ctxb);

  // 4) out projection + bias + residual(yconv) -> res1 (overwrites qkv start)
  sgemm_kernel<true><<<dim3(1024 / 128, MTOT / 128), blk256, 0, stream>>>(
      ctxb, wo, res1, 1024, 1024, 1024, 1024,
      bo, yconv, nullptr, 0, 0, 0);

  // 5) LN1 -> x1
  ln_kernel<<<dim3(MTOT), blk256, 0, stream>>>(res1, nullptr, ln1_g, ln1_b, x1);

  // 6) gate softmax -> probs
  gate_kernel<<<dim3(MTOT), dim3(64), 0, stream>>>(x1, gate_w, gate_b, probs);

  // 7) MoE: per expert, h = relu(x1@w1[e]+b1[e]); moe (+)= probs[:,e]*(h@w2[e]+b2[e])
  //    (ctx and yconv dead -> hbuf takes all of A)
  for (int e = 0; e < NEXP; ++e) {
    const float* w1e = w1 + (size_t)e * DIMC * DFFC;
    const float* b1e = b1 + (size_t)e * DFFC;
    const float* w2e = w2 + (size_t)e * DFFC * DIMC;
    const float* b2e = b2 + (size_t)e * DIMC;
    sgemm_kernel<false><<<dim3(DFFC / 128, MTOT / 128), blk256, 0, stream>>>(
        x1, w1e, hbuf, 1024, 1024, DFFC, DFFC,
        b1e, nullptr, nullptr, 0, 1 /*relu*/, 0);
    sgemm_kernel<false><<<dim3(DIMC / 128, MTOT / 128), blk256, 0, stream>>>(
        hbuf, w2e, moe, DFFC, DFFC, 1024, 1024,
        b2e, nullptr, probs + e, NEXP, 0, e > 0 /*accum*/);
  }

  // 8) LN2(x1 + moe) -> out
  ln_kernel<<<dim3(MTOT), blk256, 0, stream>>>(x1, moe, ln2_g, ln2_b, out);
}

// Round 3
// 3919.110 us; speedup vs baseline: 2.3142x; 2.3142x over previous
//
#include <hip/hip_runtime.h>

// Problem constants
#define SEQ   2048
#define NBAT  2
#define MTOT  4096        // NBAT*SEQ
#define DIMC  1024
#define DFFC  4096
#define NEXP  8
#define NHEAD 16
//
// ws layout (floats), lifetime-overlapped, peak ~118 MB (same as round 2):
//  A [0, 16.77M) : im2col+yconv -> ctx -> MoE hidden
//  B [16.77M, 29.36M) : wpack -> qkv -> res1|x1|moe
//  probs [29.36M, +32K)

typedef __attribute__((ext_vector_type(8)))  __bf16          bf16x8;
typedef __attribute__((ext_vector_type(8)))  unsigned short  us8;
typedef __attribute__((ext_vector_type(16))) float           f32x16;

// fp32 -> (hi, lo) bf16 split: a ~= hi + lo, residual ~2^-16 relative.
__device__ __forceinline__ void split2(float a, unsigned short& h, unsigned short& l)
{
  const unsigned ua = __float_as_uint(a);
  h = (unsigned short)(ua >> 16);                    // truncated hi
  const float r = a - __uint_as_float(ua & 0xffff0000u);
  l = (unsigned short)((__float_as_uint(r) + 0x8000u) >> 16);  // RN lo
}

__device__ __forceinline__ bf16x8 ld_frag(const unsigned short* p)
{
  return __builtin_bit_cast(bf16x8, *(const us8*)p);
}

__device__ __forceinline__ f32x16 mfma32(bf16x8 a, bf16x8 b, f32x16 c)
{
  return __builtin_amdgcn_mfma_f32_32x32x16_bf16(a, b, c, 0, 0, 0);
}

// Stage 128 rows x 32 k of fp32 (row-major, leading dim ld) into split-bf16
// LDS fragment layout dst[hi/lo][kg][row][j]  (element (row, kg*8+j)).
__device__ __forceinline__ void stage_rows(const float* __restrict__ src0, size_t ld,
                                           int t, unsigned short (*dst)[4][128][8])
{
  const int row = t >> 1, ks = (t & 1) * 16;
  const float* src = src0 + (size_t)row * ld + ks;
#pragma unroll
  for (int q = 0; q < 4; ++q) {
    const float4 v = *(const float4*)&src[q * 4];
    const int kk = ks + q * 4;
    const int kg = kk >> 3, j0 = kk & 7;             // j0 in {0,4}
    union { unsigned short s[4]; unsigned long long v64; } ph, pl;
    split2(v.x, ph.s[0], pl.s[0]);
    split2(v.y, ph.s[1], pl.s[1]);
    split2(v.z, ph.s[2], pl.s[2]);
    split2(v.w, ph.s[3], pl.s[3]);
    *(unsigned long long*)&dst[0][kg][row][j0] = ph.v64;
    *(unsigned long long*)&dst[1][kg][row][j0] = pl.v64;
  }
}

// ---------------------------------------------------------------------------
// bf16x3 split-precision MFMA GEMM: C[M,N] = A[M,K] @ B + epilogue.
//   BT=false: B is (K,N) row-major.  BT=true: B is (N,K) row-major.
// Tile 128x128, BK=32, 256 threads = 4 waves, each wave a 64x64 quadrant
// (2x2 fragments of v_mfma_f32_32x32x16_bf16).
// Epilogue: +bias[N], relu, *row_scale[m], +residual[M,N], +=C (accum).
// Requires M%128==0, N%128==0, K%32==0.
// ---------------------------------------------------------------------------
template<bool BT>
__global__ __launch_bounds__(256)
void mgemm_kernel(const float* __restrict__ Ag, const float* __restrict__ Bg,
                  float* __restrict__ C, int K, int lda, int ldb, int ldc,
                  const float* __restrict__ bias,
                  const float* __restrict__ residual,
                  const float* __restrict__ row_scale, int rs_stride,
                  int do_relu, int do_accum)
{
  __shared__ unsigned short As[2][4][128][8];   // 16 KB
  __shared__ unsigned short Bs[2][4][128][8];   // 16 KB
  const int t  = threadIdx.x;
  const int m0 = blockIdx.y * 128;
  const int n0 = blockIdx.x * 128;
  const int wid = t >> 6, lane = t & 63;
  const int wr = wid >> 1, wc = wid & 1;        // 2x2 wave grid
  const int l31 = lane & 31, lhi = lane >> 5;

  f32x16 acc[2][2];
#pragma unroll
  for (int i = 0; i < 2; ++i)
#pragma unroll
    for (int j = 0; j < 2; ++j)
#pragma unroll
      for (int r = 0; r < 16; ++r) acc[i][j][r] = 0.f;

  for (int k0 = 0; k0 < K; k0 += 32) {
    __syncthreads();   // guard LDS reuse from previous iteration's readers
    // ---- stage A (128 x 32), split hi/lo ----
    stage_rows(&Ag[(size_t)m0 * lda + k0], lda, t, As);
    // ---- stage B ----
    if (BT) {
      // B is (N,K): rows are n -> identical pattern to A
      stage_rows(&Bg[(size_t)n0 * ldb + k0], ldb, t, Bs);
    } else {
      // B is (K,N): gather a column of 16 k's per thread (coalesced across lanes)
      const int col = t & 127, kh = t >> 7;     // kh: k half (0/1)
      const float* src = &Bg[(size_t)(k0 + kh * 16) * ldb + n0 + col];
      float vv[16];
#pragma unroll
      for (int kk = 0; kk < 16; ++kk) vv[kk] = src[(size_t)kk * ldb];
#pragma unroll
      for (int q = 0; q < 4; ++q) {
        const int kg = kh * 2 + (q >> 1);
        const int j0 = (q & 1) * 4;
        union { unsigned short s[4]; unsigned long long v64; } ph, pl;
#pragma unroll
        for (int i = 0; i < 4; ++i) split2(vv[q * 4 + i], ph.s[i], pl.s[i]);
        *(unsigned long long*)&Bs[0][kg][col][j0] = ph.v64;
        *(unsigned long long*)&Bs[1][kg][col][j0] = pl.v64;
      }
    }
    __syncthreads();

    // ---- compute: 2 k-substeps of 16, 3 split terms, 2x2 fragments ----
#pragma unroll
    for (int ks = 0; ks < 2; ++ks) {
      bf16x8 ah[2], al[2], bh[2], bl[2];
#pragma unroll
      for (int f = 0; f < 2; ++f) {
        ah[f] = ld_frag(&As[0][ks * 2 + lhi][wr * 64 + f * 32 + l31][0]);
        al[f] = ld_frag(&As[1][ks * 2 + lhi][wr * 64 + f * 32 + l31][0]);
        bh[f] = ld_frag(&Bs[0][ks * 2 + lhi][wc * 64 + f * 32 + l31][0]);
        bl[f] = ld_frag(&Bs[1][ks * 2 + lhi][wc * 64 + f * 32 + l31][0]);
      }
#pragma unroll
      for (int mf = 0; mf < 2; ++mf)
#pragma unroll
        for (int nf = 0; nf < 2; ++nf) {
          acc[mf][nf] = mfma32(al[mf], bh[nf], acc[mf][nf]);
          acc[mf][nf] = mfma32(ah[mf], bl[nf], acc[mf][nf]);
          acc[mf][nf] = mfma32(ah[mf], bh[nf], acc[mf][nf]);
        }
    }
  }

  // ---- epilogue: C/D layout col=lane&31, row=(r&3)+8*(r>>2)+4*lhi ----
#pragma unroll
  for (int mf = 0; mf < 2; ++mf)
#pragma unroll
    for (int nf = 0; nf < 2; ++nf) {
      const int cn  = n0 + wc * 64 + nf * 32 + l31;
      const float bia = bias ? bias[cn] : 0.f;
#pragma unroll
      for (int r = 0; r < 16; ++r) {
        const int row = m0 + wr * 64 + mf * 32 + (r & 3) + 8 * (r >> 2) + 4 * lhi;
        float v = acc[mf][nf][r] + bia;
        if (do_relu)   v = fmaxf(v, 0.f);
        if (row_scale) v *= row_scale[(size_t)row * rs_stride];
        if (residual)  v += residual[(size_t)row * ldc + cn];
        float* cp = &C[(size_t)row * ldc + cn];
        if (do_accum)  v += *cp;
        *cp = v;
      }
    }
}

// ---------------------------------------------------------------------------
// conv weight repack: wpack[t*1024 + i][o] = conv_w[o][i][t]
// ---------------------------------------------------------------------------
__global__ __launch_bounds__(256)
void wpack_kernel(const float* __restrict__ cw, float* __restrict__ wp)
{
  const int idx = blockIdx.x * 256 + threadIdx.x;   // < 3072*1024
  if (idx >= 3072 * 1024) return;
  const int o  = idx & 1023;
  const int k  = idx >> 10;
  const int tt = k >> 10;
  const int i  = k & 1023;
  wp[idx] = cw[(size_t)o * 3072 + i * 3 + tt];
}

// ---------------------------------------------------------------------------
// im2col with zero padding (per batch): col[m][t*1024+i] = x[b, s+t-1, i]
// ---------------------------------------------------------------------------
__global__ __launch_bounds__(256)
void im2col_kernel(const float* __restrict__ x, float* __restrict__ col)
{
  const size_t idx = (size_t)blockIdx.x * 256 + threadIdx.x;  // < 4096*3072
  if (idx >= (size_t)MTOT * 3072) return;
  const int j  = (int)(idx % 3072);
  const int m  = (int)(idx / 3072);
  const int tt = j >> 10;
  const int i  = j & 1023;
  const int b  = m >> 11;
  const int s  = m & 2047;
  const int sr = s + tt - 1;
  float v = 0.f;
  if (sr >= 0 && sr < SEQ) v = x[((size_t)(b * SEQ + sr) << 10) + i];
  col[idx] = v;
}

// ---------------------------------------------------------------------------
// Fused flash-style attention, fp32 (unchanged from round 2 baseline).
// ---------------------------------------------------------------------------
__global__ __launch_bounds__(256)
void attn_kernel(const float* __restrict__ qkv, float* __restrict__ ctx)
{
  const int qt = blockIdx.x, h = blockIdx.y, b = blockIdx.z;
  const int t = threadIdx.x;
  const int lane = t & 63;
  const int qr = t >> 2, quad = t & 3;
  __shared__ float Ks[64 * 64];
  __shared__ float Vs[64 * 64];
  const size_t base = (size_t)b * SEQ * 3072;
  const int hoff = h * 64;

  float4 qreg[16];
  {
    const float* qrow = &qkv[base + (size_t)(qt * 64 + qr) * 3072 + hoff];
#pragma unroll
    for (int d4 = 0; d4 < 16; ++d4) qreg[d4] = *(const float4*)&qrow[d4 * 4];
  }

  float m_run = -1e30f, l_run = 0.f;
  float4 ctx4[4];
#pragma unroll
  for (int j = 0; j < 4; ++j) ctx4[j] = make_float4(0.f, 0.f, 0.f, 0.f);

  for (int kt = 0; kt < SEQ / 64; ++kt) {
    __syncthreads();
    for (int i = t; i < 64 * 16; i += 256) {
      const int r  = i >> 4;
      const int c4 = i & 15;
      const int cs = c4 ^ ((r >> 4) << 2);
      const float* src = &qkv[base + (size_t)(kt * 64 + r) * 3072 + 1024 + hoff + c4 * 4];
      *(float4*)&Ks[r * 64 + cs * 4] = *(const float4*)src;
      *(float4*)&Vs[r * 64 + cs * 4] = *(const float4*)&src[1024];
    }
    __syncthreads();

    float p[16];
    float tmax = -1e30f;
#pragma unroll
    for (int kk = 0; kk < 16; ++kk) {
      const int k = quad * 16 + kk;
      const float* krow = &Ks[k * 64];
      const int sw = (k >> 4) << 2;
      float a = 0.f;
#pragma unroll
      for (int d4 = 0; d4 < 16; ++d4) {
        const float4 kv = *(const float4*)&krow[(d4 ^ sw) * 4];
        a = __builtin_fmaf(qreg[d4].x, kv.x, a);
        a = __builtin_fmaf(qreg[d4].y, kv.y, a);
        a = __builtin_fmaf(qreg[d4].z, kv.z, a);
        a = __builtin_fmaf(qreg[d4].w, kv.w, a);
      }
      p[kk] = a * 0.125f;
      tmax = fmaxf(tmax, p[kk]);
    }
    tmax = fmaxf(tmax, __shfl_xor(tmax, 1, 64));
    tmax = fmaxf(tmax, __shfl_xor(tmax, 2, 64));
    const float m_new = fmaxf(m_run, tmax);
    const float resc  = __expf(m_run - m_new);
    float l_tile = 0.f;
#pragma unroll
    for (int kk = 0; kk < 16; ++kk) { p[kk] = __expf(p[kk] - m_new); l_tile += p[kk]; }
    l_tile += __shfl_xor(l_tile, 1, 64);
    l_tile += __shfl_xor(l_tile, 2, 64);
    l_run = l_run * resc + l_tile;
    m_run = m_new;
#pragma unroll
    for (int j = 0; j < 4; ++j) {
      ctx4[j].x *= resc; ctx4[j].y *= resc; ctx4[j].z *= resc; ctx4[j].w *= resc;
    }
#pragma unroll
    for (int sq = 0; sq < 4; ++sq) {
#pragma unroll
      for (int kk = 0; kk < 16; ++kk) {
        const int k = sq * 16 + kk;
        const float pv = __shfl(p[kk], (lane & ~3) | sq, 64);
        const float* vrow = &Vs[k * 64];
        const int sw = (k >> 4) << 2;
#pragma unroll
        for (int j = 0; j < 4; ++j) {
          const int c4 = (quad * 4 + j) ^ sw;
          const float4 vv = *(const float4*)&vrow[c4 * 4];
          ctx4[j].x = __builtin_fmaf(pv, vv.x, ctx4[j].x);
          ctx4[j].y = __builtin_fmaf(pv, vv.y, ctx4[j].y);
          ctx4[j].z = __builtin_fmaf(pv, vv.z, ctx4[j].z);
          ctx4[j].w = __builtin_fmaf(pv, vv.w, ctx4[j].w);
        }
      }
    }
  }
  const float inv_l = 1.f / l_run;
  float* dst = &ctx[(size_t)((size_t)b * SEQ + qt * 64 + qr) * 1024 + hoff + quad * 16];
#pragma unroll
  for (int j = 0; j < 4; ++j) {
    float4 o = ctx4[j];
    o.x *= inv_l; o.y *= inv_l; o.z *= inv_l; o.w *= inv_l;
    *(float4*)&dst[j * 4] = o;
  }
}

// ---------------------------------------------------------------------------
// LayerNorm over rows of 1024: out = LN(in (+ res)) * g + b.  grid = rows.
// ---------------------------------------------------------------------------
__global__ __launch_bounds__(256)
void ln_kernel(const float* __restrict__ in, const float* __restrict__ res,
               const float* __restrict__ g, const float* __restrict__ bt,
               float* __restrict__ out)
{
  const int row = blockIdx.x, t = threadIdx.x;
  const size_t off = ((size_t)row << 10) + t * 4;
  float4 v = *(const float4*)&in[off];
  if (res) {
    const float4 r = *(const float4*)&res[off];
    v.x += r.x; v.y += r.y; v.z += r.z; v.w += r.w;
  }
  float s  = v.x + v.y + v.z + v.w;
  float ss = v.x * v.x + v.y * v.y + v.z * v.z + v.w * v.w;
#pragma unroll
  for (int o = 32; o; o >>= 1) {
    s  += __shfl_xor(s, o, 64);
    ss += __shfl_xor(ss, o, 64);
  }
  __shared__ float red[8];
  if ((t & 63) == 0) { red[(t >> 6) * 2] = s; red[(t >> 6) * 2 + 1] = ss; }
  __syncthreads();
  s  = red[0] + red[2] + red[4] + red[6];
  ss = red[1] + red[3] + red[5] + red[7];
  const float mu   = s * (1.f / 1024.f);
  const float var  = ss * (1.f / 1024.f) - mu * mu;
  const float rstd = rsqrtf(var + 1e-5f);
  const float4 gg = *(const float4*)&g[t * 4];
  const float4 bb = *(const float4*)&bt[t * 4];
  float4 o;
  o.x = (v.x - mu) * rstd * gg.x + bb.x;
  o.y = (v.y - mu) * rstd * gg.y + bb.y;
  o.z = (v.z - mu) * rstd * gg.z + bb.z;
  o.w = (v.w - mu) * rstd * gg.w + bb.w;
  *(float4*)&out[off] = o;
}

// ---------------------------------------------------------------------------
// MoE gate: probs[m, 0..7] = softmax(x[m,:] @ gate_w + gate_b). 1 wave / row.
// ---------------------------------------------------------------------------
__global__ __launch_bounds__(64)
void gate_kernel(const float* __restrict__ x, const float* __restrict__ gw,
                 const float* __restrict__ gb, float* __restrict__ probs)
{
  const int m = blockIdx.x, lane = threadIdx.x;
  float acc[8];
#pragma unroll
  for (int e = 0; e < 8; ++e) acc[e] = 0.f;
  for (int k = lane; k < 1024; k += 64) {
    const float xv = x[((size_t)m << 10) + k];
    const float4 g0 = *(const float4*)&gw[k * 8];
    const float4 g1 = *(const float4*)&gw[k * 8 + 4];
    acc[0] = __builtin_fmaf(xv, g0.x, acc[0]);
    acc[1] = __builtin_fmaf(xv, g0.y, acc[1]);
    acc[2] = __builtin_fmaf(xv, g0.z, acc[2]);
    acc[3] = __builtin_fmaf(xv, g0.w, acc[3]);
    acc[4] = __builtin_fmaf(xv, g1.x, acc[4]);
    acc[5] = __builtin_fmaf(xv, g1.y, acc[5]);
    acc[6] = __builtin_fmaf(xv, g1.z, acc[6]);
    acc[7] = __builtin_fmaf(xv, g1.w, acc[7]);
  }
#pragma unroll
  for (int o = 32; o; o >>= 1)
#pragma unroll
    for (int e = 0; e < 8; ++e) acc[e] += __shfl_xor(acc[e], o, 64);
  float lg[8], mx = -1e30f;
#pragma unroll
  for (int e = 0; e < 8; ++e) { lg[e] = acc[e] + gb[e]; mx = fmaxf(mx, lg[e]); }
  float se = 0.f;
#pragma unroll
  for (int e = 0; e < 8; ++e) { lg[e] = __expf(lg[e] - mx); se += lg[e]; }
  const float inv = 1.f / se;
  if (lane < 8) probs[(size_t)m * 8 + lane] = lg[lane] * inv;
}

// ---------------------------------------------------------------------------
extern "C" void kernel_launch(void* const* d_in, const int* in_sizes, int n_in,
                              void* d_out, int out_size, void* d_ws, size_t ws_size,
                              hipStream_t stream)
{
  const float* x      = (const float*)d_in[0];
  const float* conv_w = (const float*)d_in[1];
  const float* conv_b = (const float*)d_in[2];
  const float* wqkv   = (const float*)d_in[3];
  const float* bqkv   = (const float*)d_in[4];
  const float* wo     = (const float*)d_in[5];
  const float* bo     = (const float*)d_in[6];
  const float* ln1_g  = (const float*)d_in[7];
  const float* ln1_b  = (const float*)d_in[8];
  const float* gate_w = (const float*)d_in[9];
  const float* gate_b = (const float*)d_in[10];
  const float* w1     = (const float*)d_in[11];
  const float* b1     = (const float*)d_in[12];
  const float* w2     = (const float*)d_in[13];
  const float* b2     = (const float*)d_in[14];
  const float* ln2_g  = (const float*)d_in[15];
  const float* ln2_b  = (const float*)d_in[16];
  float* out = (float*)d_out;
  float* ws  = (float*)d_ws;

  // Lifetime-overlapped scratch regions (floats). Peak footprint ~118 MB.
  float* A = ws;                        // 16,777,216 floats
  float* B = ws + 16777216;             // 12,582,912 floats
  float* probs = B + 12582912;          //     32,768 floats
  float* im2c  = A;                     // conv staging
  float* yconv = A + 12582912;          // conv output
  float* ctxb  = A;                     // attention output (im2c dead)
  float* hbuf  = A;                     // MoE hidden (ctx/yconv dead)
  float* wpk   = B;                     // packed conv weights
  float* qkvb  = B;                     // qkv (wpk dead)
  float* res1  = B;                     // post-attn residual sum
  float* x1    = B + 4194304;           // LN1 output
  float* moe   = B + 8388608;           // MoE accumulator

  const dim3 blk256(256);

  // 1) conv as GEMM: repack weights + im2col, then (4096x3072)@(3072x1024)
  wpack_kernel<<<dim3((3072 * 1024 + 255) / 256), blk256, 0, stream>>>(conv_w, wpk);
  im2col_kernel<<<dim3((MTOT * 3072 + 255) / 256), blk256, 0, stream>>>(x, im2c);
  mgemm_kernel<false><<<dim3(1024 / 128, MTOT / 128), blk256, 0, stream>>>(
      im2c, wpk, yconv, 3072, 3072, 1024, 1024,
      conv_b, nullptr, nullptr, 0, 0, 0);

  // 2) QKV projection: (4096x1024) @ wqkv^T + bqkv
  mgemm_kernel<true><<<dim3(3072 / 128, MTOT / 128), blk256, 0, stream>>>(
      yconv, wqkv, qkvb, 1024, 1024, 1024, 3072,
      bqkv, nullptr, nullptr, 0, 0, 0);

  // 3) fused attention -> ctx
  attn_kernel<<<dim3(SEQ / 64, NHEAD, NBAT), blk256, 0, stream>>>(qkvb, ctxb);

  // 4) out projection + bias + residual(yconv) -> res1
  mgemm_kernel<true><<<dim3(1024 / 128, MTOT / 128), blk256, 0, stream>>>(
      ctxb, wo, res1, 1024, 1024, 1024, 1024,
      bo, yconv, nullptr, 0, 0, 0);

  // 5) LN1 -> x1
  ln_kernel<<<dim3(MTOT), blk256, 0, stream>>>(res1, nullptr, ln1_g, ln1_b, x1);

  // 6) gate softmax -> probs
  gate_kernel<<<dim3(MTOT), dim3(64), 0, stream>>>(x1, gate_w, gate_b, probs);

  // 7) MoE: per expert, h = relu(x1@w1[e]+b1[e]); moe (+)= probs[:,e]*(h@w2[e]+b2[e])
  for (int e = 0; e < NEXP; ++e) {
    const float* w1e = w1 + (size_t)e * DIMC * DFFC;
    const float* b1e = b1 + (size_t)e * DFFC;
    const float* w2e = w2 + (size_t)e * DFFC * DIMC;
    const float* b2e = b2 + (size_t)e * DIMC;
    mgemm_kernel<false><<<dim3(DFFC / 128, MTOT / 128), blk256, 0, stream>>>(
        x1, w1e, hbuf, 1024, 1024, DFFC, DFFC,
        b1e, nullptr, nullptr, 0, 1 /*relu*/, 0);
    mgemm_kernel<false><<<dim3(DIMC / 128, MTOT / 128), blk256, 0, stream>>>(
        hbuf, w2e, moe, DFFC, DFFC, 1024, 1024,
        b2e, nullptr, probs + e, NEXP, 0, e > 0 /*accum*/);
  }

  // 8) LN2(x1 + moe) -> out
  ln_kernel<<<dim3(MTOT), blk256, 0, stream>>>(x1, moe, ln2_g, ln2_b, out);
}